// Round 6
// baseline (49.173 us; speedup 1.0000x reference)
//
#include <hip/hip_runtime.h>

// CGP coupler, latency-optimized L2-direct gather form.
//
// Structure (validated on-device R3-R5): entries come in runs of 32 with
// consecutive r1/r2/ro, constant cg, 32-aligned bases, a,b < 1024. So:
//   out[:, o:o+32] += cg_s * x1[:, a:a+32] * x2[:, b:b+32]
// over nseg = K/32 segments, avg ~2 segments per output 32-block (ob).
//
// R5 lesson: per-ob serial chains (~550cy/segment) dominate. Fixes here:
//  - each wave owns 4 rows = two independent 2-row FMA chains
//  - per-ob counts padded to EVEN -> inner loop does 2 segments/iter, no
//    tail; descriptor pair = one s_load_dwordx4; 8 gathers in flight
//  - grid = 2048 blocks (8/CU exactly, zero tail), each wave streams ~18
//    obs; no LDS, no barriers; XCD swizzle keeps each XCD's 256 rows of
//    x1/x2 (2 MB) resident in its private L2.

#define NOB_MAX 512
#define NSPLIT  4       // ob-range splits; grid = (B/4) * NSPLIT

// ---- pass 1: histogram output blocks ----
__global__ void seg_count(const int* __restrict__ ro, int nseg,
                          int* __restrict__ cnt)
{
    int s = blockIdx.x * blockDim.x + threadIdx.x;
    if (s >= nseg) return;
    atomicAdd(&cnt[ro[s << 5] >> 5], 1);
}

// ---- pass 2: exclusive scan of EVEN-padded per-ob counts ----
__global__ __launch_bounds__(512) void scan_kernel(const int* __restrict__ cnt,
                                                   int* __restrict__ off, int nob)
{
    __shared__ int buf[512];
    int t = threadIdx.x;
    int c = (t < nob) ? cnt[t] : 0;
    buf[t] = (c + 1) & ~1;              // round up to even
    __syncthreads();
    for (int d = 1; d < 512; d <<= 1) {
        int v = (t >= d) ? buf[t - d] : 0;
        __syncthreads();
        buf[t] += v;
        __syncthreads();
    }
    if (t < nob) off[t + 1] = buf[t];
    if (t == 0) off[0] = 0;
}

// ---- pass 3: O(nseg) bucket fill; padded slots stay zero (cg=0, a=b=0)
//      from the memset -> harmless fma. Order within ob arbitrary (fp
//      reorder noise ~1e-5 << 0.29 threshold). ----
__global__ void csr_fill(const int* __restrict__ r1, const int* __restrict__ r2,
                         const int* __restrict__ ro, const float* __restrict__ cg,
                         const int* __restrict__ off, int* __restrict__ rank,
                         int nseg, uint2* __restrict__ csr)
{
    int s = blockIdx.x * blockDim.x + threadIdx.x;
    if (s >= nseg) return;
    int k = s << 5;
    int ob = ro[k] >> 5;
    int pos = off[ob] + atomicAdd(&rank[ob], 1);
    uint2 d;
    d.x = (unsigned int)r1[k] | ((unsigned int)r2[k] << 16);
    d.y = __float_as_uint(cg[k]);
    csr[pos] = d;
}

// ---- main ----
__global__ __launch_bounds__(256) void cgp_main(const float* __restrict__ x1,
                                                const float* __restrict__ x2,
                                                const uint2* __restrict__ csr,
                                                const int* __restrict__ off,
                                                float* __restrict__ out,
                                                int in_dim, int out_dim,
                                                int obs_per_split)
{
    // bijective XCD swizzle (gridDim.x % 8 == 0). split is the fast axis in
    // each XCD's contiguous chunk -> one XCD owns a contiguous band of
    // row-groups (256 rows = 2 MB of x1+x2 -> resident in its 4 MiB L2).
    const int lin   = blockIdx.x;
    const int chunk = gridDim.x >> 3;
    const int sw    = (lin & 7) * chunk + (lin >> 3);
    const int split  = sw & (NSPLIT - 1);
    const int rowgrp = sw >> 2;            // log2(NSPLIT) == 2
    const int r0     = rowgrp << 2;        // 4 rows per block

    const int wid  = threadIdx.x >> 6;     // wave 0..3
    const int lane = threadIdx.x & 63;
    const int half = lane >> 5;            // row within a 2-row chain
    const int t    = lane & 31;            // channel within 32-block

    // two independent row-chains per wave: rows {r0+half} and {r0+2+half}
    const float* __restrict__ p1a = x1 + (size_t)(r0 + half) * in_dim + t;
    const float* __restrict__ p2a = x2 + (size_t)(r0 + half) * in_dim + t;
    const float* __restrict__ p1b = p1a + 2 * (size_t)in_dim;
    const float* __restrict__ p2b = p2a + 2 * (size_t)in_dim;
    float* __restrict__ o_a = out + (size_t)(r0 + half) * out_dim + t;
    float* __restrict__ o_b = o_a + 2 * (size_t)out_dim;

    const int ob_end = (split + 1) * obs_per_split;

    for (int ob = split * obs_per_split + wid; ob < ob_end; ob += 4) {
        const int s0 = off[ob];            // wave-uniform -> s_load
        const int s1 = off[ob + 1];
        float accA = 0.0f, accB = 0.0f;
        for (int s = s0; s < s1; s += 2) { // count is even: no tail
            const uint2 d0 = csr[s];       // pair merges to s_load_dwordx4
            const uint2 d1 = csr[s + 1];
            {
                const int a = (int)(d0.x & 0xFFFFu);
                const int b = (int)(d0.x >> 16);
                const float c = __uint_as_float(d0.y);
                accA = fmaf(c, p1a[a] * p2a[b], accA);
                accB = fmaf(c, p1b[a] * p2b[b], accB);
            }
            {
                const int a = (int)(d1.x & 0xFFFFu);
                const int b = (int)(d1.x >> 16);
                const float c = __uint_as_float(d1.y);
                accA = fmaf(c, p1a[a] * p2a[b], accA);
                accB = fmaf(c, p1b[a] * p2b[b], accB);
            }
        }
        o_a[ob << 5] = accA;
        o_b[ob << 5] = accB;
    }
}

extern "C" void kernel_launch(void* const* d_in, const int* in_sizes, int n_in,
                              void* d_out, int out_size, void* d_ws, size_t ws_size,
                              hipStream_t stream)
{
    const float* x1 = (const float*)d_in[0];
    const float* x2 = (const float*)d_in[1];
    const float* cg = (const float*)d_in[2];
    const int*   r1 = (const int*)d_in[3];
    const int*   r2 = (const int*)d_in[4];
    const int*   ro = (const int*)d_in[5];
    float* out = (float*)d_out;

    const int in_dim  = 1024;                  // fixed by METADATA
    const int B       = in_sizes[0] / in_dim;  // 2048
    const int out_dim = out_size / B;          // 8960
    const int K       = in_sizes[2];
    const int nseg    = K >> 5;                // all degs are 32
    const int nob     = out_dim >> 5;          // 280
    const int nsegPad = nseg + nob;            // upper bound after even-pad

    // ---- workspace layout (16B-aligned carving) ----
    auto align16 = [](size_t v) { return (v + 15) & ~(size_t)15; };
    char* ws = (char*)d_ws;
    uint2* csrD = (uint2*)ws;  ws += align16((size_t)nsegPad * sizeof(uint2));
    int*   cnt  = (int*)ws;    ws += align16((size_t)NOB_MAX * sizeof(int));
    int*   rank = (int*)ws;    ws += align16((size_t)NOB_MAX * sizeof(int));
    int*   off  = (int*)ws;

    // zero padded csr (pad slots must be cg=0,a=b=0) and cnt+rank
    hipMemsetAsync(csrD, 0, (size_t)nsegPad * sizeof(uint2), stream);
    hipMemsetAsync(cnt, 0, 2 * NOB_MAX * sizeof(int), stream);   // cnt AND rank

    {
        int blk = 256, grd = (nseg + blk - 1) / blk;
        hipLaunchKernelGGL(seg_count, dim3(grd), dim3(blk), 0, stream, ro, nseg, cnt);
    }
    hipLaunchKernelGGL(scan_kernel, dim3(1), dim3(512), 0, stream, cnt, off, nob);
    {
        int blk = 256, grd = (nseg + blk - 1) / blk;
        hipLaunchKernelGGL(csr_fill, dim3(grd), dim3(blk), 0, stream,
                           r1, r2, ro, cg, off, rank, nseg, csrD);
    }
    {
        const int obs_per_split = nob / NSPLIT;        // 70
        const int nwg = (B >> 2) * NSPLIT;             // 512 * 4 = 2048, %8==0
        hipLaunchKernelGGL(cgp_main, dim3(nwg), dim3(256), 0, stream,
                           x1, x2, csrD, off, out, in_dim, out_dim, obs_per_split);
    }
}